// Round 4
// baseline (736.319 us; speedup 1.0000x reference)
//
#include <hip/hip_runtime.h>
#include <float.h>
#include <math.h>

#define NROWS 131072      // B*H*W = 32*64*64
#define KCB   512
#define DDIM  64
#define HWSP  4096        // H*W
#define BCHW  8388608     // 32*64*64*64

#define BM    128         // rows per block
#define BKT   128         // codes per k-tile
#define NT    4           // k-tiles (KCB/BKT)

// ---------------- kernel 1: distances + encodings + argmin + indices ----------------
// 256 threads = 16x16 grid; each thread: 8 rows x 8 codes (split 4+4 at stride 64
// so all compute-phase LDS reads are contiguous-256B or broadcast => conflict-free).
__global__ __launch_bounds__(256) void vq_main(const float* __restrict__ x,
                                               const float* __restrict__ Wc,
                                               float* __restrict__ dist,
                                               float* __restrict__ enc,
                                               float* __restrict__ idxo) {
    __shared__ float lx[DDIM][BM];    // 32 KB  [d][row] — x is NCHW: straight copy
    __shared__ float lw[DDIM][BKT];   // 32 KB  [d][k_local] — W transposed
    __shared__ float lxsq[BM];
    __shared__ float lwsq[KCB];       // 2 KB — all K, computed once in prologue

    const int t  = threadIdx.x;
    const int n0 = blockIdx.x * BM;
    const int b  = n0 >> 12;           // 128 | 4096 -> single image per block
    const int s0 = n0 & (HWSP - 1);

    // stage x tile [c][s]; global reads contiguous in s; LDS writes conflict-free
    {
        const int s = t & 127, cq = t >> 7;      // cq in {0,1}
        const float* xb = x + (size_t)b * (DDIM * HWSP) + s0 + s;
#pragma unroll
        for (int it = 0; it < 32; ++it) {
            const int c = it * 2 + cq;
            lx[c][s] = xb[(size_t)c * HWSP];
        }
    }
    // wsq for ALL 512 codes from global W (L2-resident after first blocks)
    {
#pragma unroll
        for (int kk = 0; kk < 2; ++kk) {
            const int k = t + kk * 256;
            const float4* wr = (const float4*)(Wc + (size_t)k * DDIM);
            float s = 0.f;
#pragma unroll
            for (int j = 0; j < 16; ++j) {
                const float4 v = wr[j];
                s += v.x * v.x + v.y * v.y + v.z * v.z + v.w * v.w;
            }
            lwsq[k] = s;
        }
    }
    __syncthreads();
    if (t < BM) {
        float s = 0.f;
#pragma unroll
        for (int d = 0; d < DDIM; ++d) { const float v = lx[d][t]; s += v * v; }
        lxsq[t] = s;
    }

    const int tr = t >> 4;   // rows  tr*4..+3  and  64+tr*4..+3
    const int tc = t & 15;   // codes tc*4..+3  and  64+tc*4..+3 (per tile)

    float best[8];
    int   bidx[8];
#pragma unroll
    for (int i = 0; i < 8; ++i) { best[i] = FLT_MAX; bidx[i] = 0; }

    for (int kt = 0; kt < NT; ++kt) {
        __syncthreads();   // prev tile's lw reads done (covers lxsq/lwsq vis at kt=0)
        {   // stage W tile [d][k_local]; global reads contiguous in d
            const int d = t & 63, kq0 = t >> 6;
            const float* wb = Wc + (size_t)(kt * BKT) * DDIM + d;
#pragma unroll
            for (int it = 0; it < 32; ++it) {
                const int kq = it * 4 + kq0;
                lw[d][kq] = wb[(size_t)kq * DDIM];
            }
        }
        __syncthreads();

        float acc[8][8] = {};
#pragma unroll 4
        for (int d = 0; d < DDIM; ++d) {
            const float4 xv0 = *(const float4*)&lx[d][tr * 4];
            const float4 xv1 = *(const float4*)&lx[d][64 + tr * 4];
            const float4 wv0 = *(const float4*)&lw[d][tc * 4];
            const float4 wv1 = *(const float4*)&lw[d][64 + tc * 4];
            const float xv[8] = {xv0.x, xv0.y, xv0.z, xv0.w, xv1.x, xv1.y, xv1.z, xv1.w};
            const float wv[8] = {wv0.x, wv0.y, wv0.z, wv0.w, wv1.x, wv1.y, wv1.z, wv1.w};
#pragma unroll
            for (int i = 0; i < 8; ++i)
#pragma unroll
                for (int j = 0; j < 8; ++j)
                    acc[i][j] += xv[i] * wv[j];
        }

        const int kb = kt * BKT;
        const float4 z4 = make_float4(0.f, 0.f, 0.f, 0.f);
#pragma unroll
        for (int h = 0; h < 2; ++h)
#pragma unroll
        for (int i = 0; i < 4; ++i) {
            const int r = h * 64 + tr * 4 + i;
            const int n = n0 + r;
            const float xs = lxsq[r];
            float* drow = &dist[(size_t)n * KCB + kb];
            float* erow = &enc [(size_t)n * KCB + kb];
#pragma unroll
            for (int g = 0; g < 2; ++g) {
                const int kc = g * 64 + tc * 4;
                const float4 wq = *(const float4*)&lwsq[kb + kc];
                float4 dv;
                dv.x = xs + wq.x - 2.f * acc[h * 4 + i][g * 4 + 0];
                dv.y = xs + wq.y - 2.f * acc[h * 4 + i][g * 4 + 1];
                dv.z = xs + wq.z - 2.f * acc[h * 4 + i][g * 4 + 2];
                dv.w = xs + wq.w - 2.f * acc[h * 4 + i][g * 4 + 3];
                *(float4*)&drow[kc] = dv;
                *(float4*)&erow[kc] = z4;
                const float dd[4] = {dv.x, dv.y, dv.z, dv.w};
#pragma unroll
                for (int j = 0; j < 4; ++j) {
                    const int kk = kb + kc + j;     // strictly increasing per thread
                    const int a  = h * 4 + i;
                    if (dd[j] < best[a] || (dd[j] == best[a] && kk < bidx[a])) {
                        best[a] = dd[j]; bidx[a] = kk;
                    }
                }
            }
        }
    }

    // argmin reduce across the 16 tc-lanes sharing each tr (numpy first-min tie-break)
#pragma unroll
    for (int off = 8; off >= 1; off >>= 1)
#pragma unroll
        for (int i = 0; i < 8; ++i) {
            const float od = __shfl_xor(best[i], off);
            const int   oi = __shfl_xor(bidx[i], off);
            if (od < best[i] || (od == best[i] && oi < bidx[i])) { best[i] = od; bidx[i] = oi; }
        }

    __syncthreads();   // all enc zero-stores drained (vmcnt(0) before barrier) pre fix-up
    if (tc == 0) {
#pragma unroll
        for (int h = 0; h < 2; ++h)
#pragma unroll
        for (int i = 0; i < 4; ++i) {
            const int r  = h * 64 + tr * 4 + i;
            const int n  = n0 + r;
            const int bi = bidx[h * 4 + i];
            idxo[n] = (float)bi;
            enc[(size_t)n * KCB + bi] = 1.0f;
        }
    }
}

// ---------------- kernel 2: quantized (gather + transpose back to NCHW) ----------------
__global__ __launch_bounds__(256) void vq_quant(const float* __restrict__ Wc,
                                                const float* __restrict__ idxf,
                                                float* __restrict__ qout) {
    __shared__ float lq[64][65];   // [row][c], pad 65 -> conflict-free column reads
    __shared__ int   codes[64];

    const int t  = threadIdx.x;
    const int n0 = blockIdx.x * 64;
    const int b  = n0 >> 12;
    const int s0 = n0 & (HWSP - 1);

    if (t < 64) codes[t] = (int)idxf[n0 + t];
    __syncthreads();
    {   // gather codebook rows; coalesced (64 lanes = one 256B row)
        const int c = t & 63, rq = t >> 6;
#pragma unroll
        for (int it = 0; it < 16; ++it) {
            const int r = it * 4 + rq;
            lq[r][c] = Wc[(size_t)codes[r] * DDIM + c];
        }
    }
    __syncthreads();
    {   // write NCHW; contiguous in s
        const int s = t & 63, cq = t >> 6;
        float* qb = qout + (size_t)b * (DDIM * HWSP) + s0 + s;
#pragma unroll
        for (int it = 0; it < 16; ++it) {
            const int c = it * 4 + cq;
            qb[(size_t)c * HWSP] = lq[s][c];
        }
    }
}

// ---------------- kernel 3: perplexity from indices (single block, LDS hist) ----------------
__global__ __launch_bounds__(1024) void vq_perp(const float* __restrict__ idxf,
                                                float* __restrict__ perp) {
    __shared__ unsigned int lh[KCB];
    __shared__ float red[16];
    const int t = threadIdx.x;
    if (t < KCB) lh[t] = 0u;
    if (t < 16) red[t] = 0.f;
    __syncthreads();
    const float4* p4 = (const float4*)idxf;
#pragma unroll 4
    for (int j = 0; j < 32; ++j) {          // 32768 float4 / 1024 threads
        const float4 v = p4[t + j * 1024];
        atomicAdd(&lh[(int)v.x], 1u);
        atomicAdd(&lh[(int)v.y], 1u);
        atomicAdd(&lh[(int)v.z], 1u);
        atomicAdd(&lh[(int)v.w], 1u);
    }
    __syncthreads();
    float term = 0.f;
    if (t < KCB) {
        const float p = (float)lh[t] * (1.0f / (float)NROWS);
        term = p * logf(p + 1e-10f);
    }
#pragma unroll
    for (int off = 32; off >= 1; off >>= 1) term += __shfl_down(term, off);
    if ((t & 63) == 0) red[t >> 6] = term;
    __syncthreads();
    if (t == 0) {
        float s = 0.f;
#pragma unroll
        for (int i = 0; i < 16; ++i) s += red[i];
        *perp = expf(-s);
    }
}

extern "C" void kernel_launch(void* const* d_in, const int* in_sizes, int n_in,
                              void* d_out, int out_size, void* d_ws, size_t ws_size,
                              hipStream_t stream) {
    const float* x  = (const float*)d_in[0];
    const float* Wc = (const float*)d_in[1];

    float* out = (float*)d_out;
    const size_t NK = (size_t)NROWS * KCB;
    float* dist  = out;                  // [N,K]
    float* enc   = out + NK;             // [N,K]
    float* idxo  = out + 2 * NK;         // [N,1] (indices as f32)
    float* quant = idxo + NROWS;         // [B,C,H,W]
    float* perp  = quant + (size_t)BCHW; // scalar

    (void)d_ws; (void)ws_size;           // no workspace use

    vq_main <<<NROWS / BM, 256,  0, stream>>>(x, Wc, dist, enc, idxo);
    vq_quant<<<NROWS / 64, 256,  0, stream>>>(Wc, idxo, quant);
    vq_perp <<<1,          1024, 0, stream>>>(idxo, perp);
}